// Round 20
// baseline (621.994 us; speedup 1.0000x reference)
//
#include <hip/hip_runtime.h>

// Problem constants (match reference setup_inputs)
#define BB   512
#define NN   512
#define NNZ  8192
#define EMB  64
#define HID  100
#define EXCAPB 512           // per-BATCH dup-exception capacity (mean 128, +34 sigma)
#define DUPC 0x7FFF          // col marker for dup entries (fails c<512 check in spmm)

// ---------------------------------------------------------------------------
// ws layout (bytes):
//   [0)          rc      int  [B*NNZ]  (row<<16|col, stripe-bucketed) 16,777,216
//   [16777216)   vpk     bf16 [B*NNZ]  (stripe-bucketed)               8,388,608
//   [25165824)   sstart  int  [B*9]                                       18,432
//   [26216448)   supT    bf16 [B][16kt][112col][32k]                  58,720,256
//   [84936704)   w1t     bf16 [112][64]                                   14,336
//   [84951040)   w2t     bf16 [112][128]                                  28,672
//   [84979712)   bmap_g  u32  [B][8192]  (512x512-bit dup bitmap)     16,777,216
//   [101756928)  exc_cnt int  [B]                                          2,048
//   [101758976)  exc_k   int  [B][512]  (row<<9|col)                   1,048,576
//   [102807552)  exc_v   f32  [B][512]                                 1,048,576
// total 103,856,128 <= 104,857,600 (proven). h1 bf16 [B][512][112] in d_out.
// ---------------------------------------------------------------------------
#define OFF_RC      0
#define OFF_VPK     16777216
#define OFF_SSTART  25165824
#define OFF_SUPT    26216448
#define OFF_W1T     84936704
#define OFF_W2T     84951040
#define OFF_BMAPG   84979712
#define OFF_EXCNT   101756928
#define OFF_EXK     101758976
#define OFF_EXV     102807552

typedef __attribute__((ext_vector_type(8))) short short8;
typedef __attribute__((ext_vector_type(4))) float floatx4;

__device__ __forceinline__ unsigned short f2bf(float f) {
    unsigned u = __float_as_uint(f);
    unsigned r = (u + 0x7fffu + ((u >> 16) & 1u)) >> 16;
    return (unsigned short)r;
}

__device__ __forceinline__ float bf2f(unsigned short b) {
    return __uint_as_float((unsigned)b << 16);
}

__device__ __forceinline__ short8 pack8(float4 a, float4 b) {
    short8 s;
    s[0] = (short)f2bf(a.x); s[1] = (short)f2bf(a.y);
    s[2] = (short)f2bf(a.z); s[3] = (short)f2bf(a.w);
    s[4] = (short)f2bf(b.x); s[5] = (short)f2bf(b.y);
    s[6] = (short)f2bf(b.z); s[7] = (short)f2bf(b.w);
    return s;
}

// supT k-tiled addressing: elem(b, col, k) = b*57344 + (k>>5)*3584 + col*32 + (k&31)
__device__ __forceinline__ size_t supt_addr(int batch, int col, int k) {
    return (size_t)batch * 57344 + (size_t)(k >> 5) * 3584 + (size_t)col * 32 + (k & 31);
}

// A_d lane-linear tiled address (verified r13-r19): [m:4][kt:16][k8:4][r:16][k7:8]
__device__ __forceinline__ int ad_addr(int rr, int c) {
    return (rr >> 4) * 8192 + (c >> 5) * 512 + ((c >> 3) & 3) * 128 + (rr & 15) * 8 + (c & 7);
}

// ---------------------------------------------------------------------------
// k_bucket v2: stripe-bucketed COO build + GLOBAL-bitmap dup detection.
// Dup detection pays its latency ONCE here (16 independent atomicOr/thread,
// issued first, resolved under histogram/scan); the in-spmm bitmap (r18/r19,
// ~23 us/dispatch x2) is eliminated. Losers: marked DUPC in the stream
// (spmm skips with one compare) + appended to a per-batch exception list.
// On exc overflow (>512, +34 sigma: never) entries stay unmarked.
// ---------------------------------------------------------------------------
__global__ __launch_bounds__(512) void k_bucket(
    const int* __restrict__ rows, const int* __restrict__ cols,
    const float* __restrict__ vals, int* __restrict__ rc,
    unsigned short* __restrict__ vpk, int* __restrict__ sstart,
    unsigned* __restrict__ bmap_g, int* __restrict__ exc_cnt,
    int* __restrict__ exc_k, float* __restrict__ exc_v,
    const float* __restrict__ W1, const float* __restrict__ W2,
    unsigned short* __restrict__ w1t, unsigned short* __restrict__ w2t)
{
    __shared__ int            rl[NNZ];        // 32 KB packed (r<<16)|c
    __shared__ unsigned short vh[NNZ];        // 16 KB bf16 vals
    __shared__ int            wcnt[8][8];     // [wave][stripe] counters/cursors
    __shared__ int            wbase[8][8];

    const int b   = blockIdx.x;
    const int tid = threadIdx.x;
    const int wave = tid >> 6;

    // striped weight prep: 21504 elements over 512 blocks
    {
        int pid = b + (tid << 9);
        if (pid < 7168) {
            int h = pid >> 6, k = pid & 63;
            w1t[pid] = f2bf((h < 100) ? W1[k * 100 + h] : 0.f);
        } else if (pid < 7168 + 14336) {
            int id2 = pid - 7168;
            int h = id2 >> 7, k = id2 & 127;
            w2t[id2] = f2bf((h < 100 && k < 100) ? W2[k * 100 + h] : 0.f);
        }
    }

    const int*   rb = rows + (size_t)b * NNZ;
    const int*   cb = cols + (size_t)b * NNZ;
    const float* vb = vals + (size_t)b * NNZ;

    // load all entries once into registers (16/thread)
    int rr[16], cc[16];
    float vv[16];
    #pragma unroll
    for (int i = 0; i < 16; ++i) {
        int idx = tid + i * 512;
        rr[i] = rb[idx]; cc[i] = cb[idx]; vv[i] = vb[idx];
    }

    // dup detection: 16 independent global atomicOr (latency overlaps P1/P2)
    unsigned* bm = bmap_g + (size_t)b * 8192;
    unsigned dupmask = 0;
    #pragma unroll
    for (int i = 0; i < 16; ++i) {
        unsigned bit = 1u << (cc[i] & 31);
        unsigned old = atomicOr(&bm[(rr[i] << 4) + (cc[i] >> 5)], bit);
        if (old & bit) {
            dupmask |= 1u << i;
            int e = atomicAdd(&exc_cnt[b], 1);
            if (e < EXCAPB) {
                exc_k[b * EXCAPB + e] = (rr[i] << 9) | cc[i];
                exc_v[b * EXCAPB + e] = vv[i];
            } else {
                dupmask &= ~(1u << i);    // overflow: keep entry (p ~ 0)
            }
        }
    }

    if (tid < 64) ((int*)wcnt)[tid] = 0;
    __syncthreads();

    // P1: per-(wave,stripe) histogram
    #pragma unroll
    for (int i = 0; i < 16; ++i)
        atomicAdd(&wcnt[wave][rr[i] >> 6], 1);
    __syncthreads();

    // P2: tiny serial scan (64 values, stripe-major) + stripe_start out
    if (tid == 0) {
        int acc = 0;
        #pragma unroll
        for (int s = 0; s < 8; ++s) {
            sstart[b * 9 + s] = acc;
            #pragma unroll
            for (int w = 0; w < 8; ++w) { wbase[w][s] = acc; acc += wcnt[w][s]; }
        }
        sstart[b * 9 + 8] = NNZ;
    }
    __syncthreads();
    if (tid < 64) ((int*)wcnt)[tid] = ((int*)wbase)[tid];   // cursors
    __syncthreads();

    // P3: scatter into LDS staging (bucketed by stripe; dups marked DUPC)
    #pragma unroll
    for (int i = 0; i < 16; ++i) {
        int s = rr[i] >> 6;
        int pos = atomicAdd(&wcnt[wave][s], 1);
        bool dup = (dupmask >> i) & 1;
        rl[pos] = (rr[i] << 16) | (dup ? DUPC : cc[i]);
        vh[pos] = dup ? 0 : f2bf(vv[i]);
    }
    __syncthreads();

    // P4: fully coalesced writeback
    {
        int* orc = rc + (size_t)b * NNZ;
        #pragma unroll
        for (int i = 0; i < 16; ++i) {
            int idx = tid + i * 512;
            orc[idx] = rl[idx];
        }
        unsigned* ov = (unsigned*)(vpk + (size_t)b * NNZ);
        #pragma unroll
        for (int i = 0; i < 8; ++i) {
            int p = tid + i * 512;
            ov[p] = (unsigned)vh[2 * p] | ((unsigned)vh[2 * p + 1] << 16);
        }
    }
}

// ---------------------------------------------------------------------------
// GEMM1 (MFMA): supT(k-tiled) = bf16( emb[hyper] @ W1 )^T per batch. (r12-r19)
// ---------------------------------------------------------------------------
__global__ __launch_bounds__(256) void k_gemm1_mfma(
    const int* __restrict__ hyper, const float* __restrict__ emb,
    const unsigned short* __restrict__ w1t, unsigned short* __restrict__ supT)
{
    const int lane = threadIdx.x & 63, wave = threadIdx.x >> 6;
    const int l15 = lane & 15, g4 = lane >> 4;

    short8 bq[7][2];
    #pragma unroll
    for (int ct = 0; ct < 7; ++ct)
        #pragma unroll
        for (int kt = 0; kt < 2; ++kt)
            bq[ct][kt] = *(const short8*)(w1t + (ct * 16 + l15) * 64 + kt * 32 + g4 * 8);

    const int wsid = blockIdx.x * 4 + wave;
    #pragma unroll 2
    for (int i = 0; i < 4; ++i) {
        const int  rb   = wsid * 4 + i;
        const long base = (long)rb * 16;
        const int  rid  = hyper[base + l15];
        const float* ep = emb + (long)rid * EMB + g4 * 8;
        float4 f0 = *(const float4*)(ep);
        float4 f1 = *(const float4*)(ep + 4);
        float4 f2 = *(const float4*)(ep + 32);
        float4 f3 = *(const float4*)(ep + 36);
        short8 a0 = pack8(f0, f1);
        short8 a1 = pack8(f2, f3);

        floatx4 acc[7];
        #pragma unroll
        for (int ct = 0; ct < 7; ++ct) acc[ct] = (floatx4)0.f;
        #pragma unroll
        for (int ct = 0; ct < 7; ++ct) {
            acc[ct] = __builtin_amdgcn_mfma_f32_16x16x32_bf16(a0, bq[ct][0], acc[ct], 0, 0, 0);
            acc[ct] = __builtin_amdgcn_mfma_f32_16x16x32_bf16(a1, bq[ct][1], acc[ct], 0, 0, 0);
        }

        const int batch = rb >> 5;
        const int inrow = (rb & 31) * 16 + g4 * 4;
        #pragma unroll
        for (int ct = 0; ct < 7; ++ct) {
            int col = ct * 16 + l15;
            uint2 w;
            w.x = (unsigned)f2bf(acc[ct][0]) | ((unsigned)f2bf(acc[ct][1]) << 16);
            w.y = (unsigned)f2bf(acc[ct][2]) | ((unsigned)f2bf(acc[ct][3]) << 16);
            *(uint2*)(supT + supt_addr(batch, col, inrow)) = w;
        }
    }
}

// ---------------------------------------------------------------------------
// GEMM2 (MFMA): supT(k-tiled) = bf16( h1 @ W2 )^T, h1 bf16 [512][112]. (r12-r19)
// ---------------------------------------------------------------------------
__global__ __launch_bounds__(256) void k_gemm2_mfma(
    const unsigned short* __restrict__ h1, const unsigned short* __restrict__ w2t,
    unsigned short* __restrict__ supT)
{
    const int lane = threadIdx.x & 63, wave = threadIdx.x >> 6;
    const int l15 = lane & 15, g4 = lane >> 4;
    const int ct0 = (wave & 1) ? 4 : 0;

    short8 bq[4][4];
    #pragma unroll
    for (int ctl = 0; ctl < 4; ++ctl) {
        int ct = ct0 + ctl;
        if (ct < 7)
            #pragma unroll
            for (int kt = 0; kt < 4; ++kt)
                bq[ctl][kt] = *(const short8*)(w2t + (ct * 16 + l15) * 128 + kt * 32 + g4 * 8);
    }

    const int wp = blockIdx.x * 2 + (wave >> 1);
    #pragma unroll 2
    for (int i = 0; i < 8; ++i) {
        const int  rb   = wp * 8 + i;
        const long base = (long)rb * 16;
        const unsigned short* rp = h1 + (size_t)(base + l15) * 112;

        short8 a[4];
        #pragma unroll
        for (int kt = 0; kt < 4; ++kt) {
            int k0 = kt * 32 + g4 * 8;
            short8 av = (short8)(short)0;
            if (k0 < 112) av = *(const short8*)(rp + k0);
            a[kt] = av;
        }

        floatx4 acc[4];
        #pragma unroll
        for (int ctl = 0; ctl < 4; ++ctl) acc[ctl] = (floatx4)0.f;
        #pragma unroll
        for (int ctl = 0; ctl < 4; ++ctl) {
            if (ct0 + ctl < 7) {
                #pragma unroll
                for (int kt = 0; kt < 4; ++kt)
                    acc[ctl] = __builtin_amdgcn_mfma_f32_16x16x32_bf16(a[kt], bq[ctl][kt], acc[ctl], 0, 0, 0);
            }
        }

        const int batch = rb >> 5;
        const int inrow = (rb & 31) * 16 + g4 * 4;
        #pragma unroll
        for (int ctl = 0; ctl < 4; ++ctl) {
            if (ct0 + ctl < 7) {
                int col = (ct0 + ctl) * 16 + l15;
                uint2 w;
                w.x = (unsigned)f2bf(acc[ctl][0]) | ((unsigned)f2bf(acc[ctl][1]) << 16);
                w.y = (unsigned)f2bf(acc[ctl][2]) | ((unsigned)f2bf(acc[ctl][3]) << 16);
                *(uint2*)(supT + supt_addr(batch, col, inrow)) = w;
            }
        }
    }
}

// ---------------------------------------------------------------------------
// SpMM + bias via dense-A MFMA. r15's verified structure (in-loop B loads,
// 64 us floor) + stripe-bucketed input. P2 is an ATOMIC-FREE predicated
// scatter (dups pre-marked DUPC by k_bucket); the tiny exception pass folds
// the batch's ~128 dups (LDS-staged, ~16 per stripe).
// ---------------------------------------------------------------------------
template<bool FINAL>
__global__ __launch_bounds__(512, 4) void k_spmm_mfma(
    const int* __restrict__ sstart, const int* __restrict__ rc,
    const unsigned short* __restrict__ vpk, const unsigned short* __restrict__ supT,
    const int* __restrict__ exc_cnt, const int* __restrict__ exc_k,
    const float* __restrict__ exc_v, const float* __restrict__ bias,
    unsigned short* __restrict__ h1, float* __restrict__ out)
{
    __shared__ unsigned short Ad[64 * 512];      // 65,536 B
    __shared__ int            lk[EXCAPB];        //  2 KB
    __shared__ float          lv[EXCAPB];        //  2 KB

    const int tid    = threadIdx.x;
    // XCD-locality swizzle (8 XCDs, round-robin blockIdx%8 -> XCD)
    const int xcd    = blockIdx.x & 7;
    const int local  = blockIdx.x >> 3;          // 0..511
    const int batch  = xcd * 64 + (local >> 3);
    const int stripe = local & 7;
    const int r0     = stripe * 64;

    const int lane = tid & 63, wave = tid >> 6;
    const int l15 = lane & 15, g4 = lane >> 4;
    const int ng  = wave & 3, kh = wave >> 2;
    const int nt0 = ng * 2;
    const bool two = (nt0 + 1) < 7;              // ng=3 owns only n-tile 6
    const int ktb = kh * 8;

    // P0: issue this stripe's COO entries + exception list EARLY
    const int s0 = sstart[batch * 9 + stripe];
    const int e0 = sstart[batch * 9 + stripe + 1];
    const int ne = min(exc_cnt[batch], EXCAPB);
    const int*            rcb = rc + (size_t)batch * NNZ;
    const unsigned short* vvb = vpk + (size_t)batch * NNZ;
    int            pc[3];
    unsigned short pv[3];
    #pragma unroll
    for (int i = 0; i < 3; ++i) {
        int idx = s0 + tid + i * 512;
        bool ok = idx < e0;
        pc[i] = ok ? rcb[idx] : 0;
        pv[i] = ok ? vvb[idx] : 0;
    }
    if (tid < ne) {
        lk[tid] = exc_k[batch * EXCAPB + tid];
        lv[tid] = exc_v[batch * EXCAPB + tid];
    }

    // P1: zero A_d (4096 uint4)
    {
        uint4* z = (uint4*)Ad;
        #pragma unroll
        for (int i = 0; i < 8; ++i) z[tid + i * 512] = make_uint4(0u, 0u, 0u, 0u);
    }
    __syncthreads();

    // P2: atomic-free predicated scatter (dups have c=DUPC >= 512)
    #pragma unroll
    for (int i = 0; i < 3; ++i) {
        int idx = s0 + tid + i * 512;
        if (idx < e0) {
            int rr = ((pc[i] >> 16) & 0xffff) - r0;   // 0..63
            int c  = pc[i] & 0xffff;
            if (c < 512) Ad[ad_addr(rr, c)] = pv[i];
        }
    }
    // overflow fallback (stripe count > 1536: ~never, correctness only)
    for (int idx = s0 + 1536 + tid; idx < e0; idx += 512) {
        int p = rcb[idx];
        int rr = ((p >> 16) & 0xffff) - r0;
        int c  = p & 0xffff;
        if (c < 512) Ad[ad_addr(rr, c)] = vvb[idx];
    }
    __syncthreads();

    // P2b: exception fold (~16 stripe-relevant of ~128; first-occurrence-owns,
    // multi-dup safe, race-free — keys unique per (row,col), row fixes stripe)
    for (int t = tid; t < ne; t += 512) {
        int key = lk[t];
        int r   = key >> 9;
        if ((r >> 6) != stripe) continue;
        bool first = true;
        for (int j = 0; j < t; ++j)
            if (lk[j] == key) { first = false; break; }
        if (first) {
            float add = lv[t];
            for (int j = t + 1; j < ne; ++j)
                if (lk[j] == key) add += lv[j];
            int rr = r & 63, c = key & 511;
            int a = ad_addr(rr, c);
            Ad[a] = f2bf(bf2f(Ad[a]) + add);
        }
    }
    __syncthreads();

    // P3: MFMA — r15's exact shape (in-loop B loads; b0/b1 scalars, no array)
    const unsigned short* b0p = supT + (size_t)batch * 57344 + (size_t)ktb * 3584
                               + (nt0 * 16 + l15) * 32 + g4 * 8;
    const unsigned short* b1p = b0p + 512;       // next n-tile
    const unsigned short* ap  = Ad + (size_t)ktb * 512 + lane * 8;  // lane-linear

    floatx4 acc[2][4];
    #pragma unroll
    for (int n = 0; n < 2; ++n)
        #pragma unroll
        for (int m = 0; m < 4; ++m) acc[n][m] = (floatx4)0.f;

    #pragma unroll 4
    for (int kt = 0; kt < 8; ++kt) {
        short8 b0 = *(const short8*)(b0p + (size_t)kt * 3584);
        short8 b1 = (short8)(short)0;
        if (two) b1 = *(const short8*)(b1p + (size_t)kt * 3584);
        #pragma unroll
        for (int m = 0; m < 4; ++m) {
            short8 a = *(const short8*)(ap + m * 8192 + kt * 512);
            acc[0][m] = __builtin_amdgcn_mfma_f32_16x16x32_bf16(a, b0, acc[0][m], 0, 0, 0);
            if (two)
                acc[1][m] = __builtin_amdgcn_mfma_f32_16x16x32_bf16(a, b1, acc[1][m], 0, 0, 0);
        }
    }
    __syncthreads();                             // all MFMAs done; A_d dead

    // P4: k-half reduction through LDS. redu[slot:4][i:32][lane:64] f32 (32KB)
    float* redu = (float*)Ad;
    if (kh == 1) {
        #pragma unroll
        for (int nn = 0; nn < 2; ++nn)
            #pragma unroll
            for (int m = 0; m < 4; ++m)
                #pragma unroll
                for (int q = 0; q < 4; ++q)
                    redu[ng * 2048 + ((nn * 4 + m) * 4 + q) * 64 + lane] = acc[nn][m][q];
    }
    __syncthreads();

    // P5: waves kh=0 add partner partials and stage C (+bias) at byte 32768
    if (kh == 0) {
        #pragma unroll
        for (int nn = 0; nn < 2; ++nn)
            #pragma unroll
            for (int m = 0; m < 4; ++m)
                #pragma unroll
                for (int q = 0; q < 4; ++q)
                    acc[nn][m][q] += redu[ng * 2048 + ((nn * 4 + m) * 4 + q) * 64 + lane];

        if (FINAL) {
            float* st = (float*)((char*)Ad + 32768);           // [64][112] f32
            #pragma unroll
            for (int nn = 0; nn < 2; ++nn) {
                int nt = nt0 + nn;
                if (nt >= 7) break;
                int col = nt * 16 + l15;
                float bi = (col < HID) ? bias[col] : 0.f;
                #pragma unroll
                for (int m = 0; m < 4; ++m) {
                    int row = m * 16 + g4 * 4;
                    #pragma unroll
                    for (int q = 0; q < 4; ++q)
                        st[(row + q) * 112 + col] = acc[nn][m][q] + bi;
                }
            }
        } else {
            unsigned short* st = (unsigned short*)((char*)Ad + 32768);  // [64][112] bf16
            #pragma unroll
            for (int nn = 0; nn < 2; ++nn) {
                int nt = nt0 + nn;
                if (nt >= 7) break;
                int col = nt * 16 + l15;
                float bi = (col < HID) ? bias[col] : 0.f;      // pad cols: acc==0 -> 0
                #pragma unroll
                for (int m = 0; m < 4; ++m) {
                    int row = m * 16 + g4 * 4;
                    #pragma unroll
                    for (int q = 0; q < 4; ++q)
                        st[(row + q) * 112 + col] = f2bf(acc[nn][m][q] + bi);
                }
            }
        }
    }
    __syncthreads();

    // P6: coalesced copy-out, all 512 threads
    if (FINAL) {
        const float* st = (const float*)((char*)Ad + 32768);
        #pragma unroll
        for (int i = 0; i < 4; ++i) {
            int flat = tid + i * 512;
            if (flat < 1600) {                   // 64 rows x 25 float4
                int row = flat / 25, wi = flat - row * 25;
                float4 v = *(const float4*)(st + row * 112 + wi * 4);
                *(float4*)(out + ((size_t)batch * NN + r0 + row) * HID + wi * 4) = v;
            }
        }
    } else {
        const unsigned short* st = (const unsigned short*)((char*)Ad + 32768);
        #pragma unroll
        for (int i = 0; i < 2; ++i) {
            int flat = tid + i * 512;
            if (flat < 896) {                    // 64 rows x 14 uint4
                int row = flat / 14, wi = flat - row * 14;
                uint4 v = *(const uint4*)(st + row * 112 + wi * 8);
                *(uint4*)(h1 + ((size_t)batch * NN + r0 + row) * 112 + wi * 8) = v;
            }
        }
    }
}

// ---------------------------------------------------------------------------
extern "C" void kernel_launch(void* const* d_in, const int* in_sizes, int n_in,
                              void* d_out, int out_size, void* d_ws, size_t ws_size,
                              hipStream_t stream)
{
    const int*   hyper = (const int*)  d_in[0];
    const int*   arows = (const int*)  d_in[1];
    const int*   acols = (const int*)  d_in[2];
    const float* avals = (const float*)d_in[3];
    const float* emb   = (const float*)d_in[4];
    const float* W1    = (const float*)d_in[5];
    const float* b1    = (const float*)d_in[6];
    const float* W2    = (const float*)d_in[7];
    const float* b2    = (const float*)d_in[8];

    float*          out = (float*)d_out;
    unsigned short* h1  = (unsigned short*)d_out;   // bf16 [B][512][112] view
    char*           ws  = (char*)d_ws;

    int*            rc     = (int*)           (ws + OFF_RC);
    unsigned short* vpk    = (unsigned short*)(ws + OFF_VPK);
    int*            sstart = (int*)           (ws + OFF_SSTART);
    unsigned short* supT   = (unsigned short*)(ws + OFF_SUPT);
    unsigned short* w1t    = (unsigned short*)(ws + OFF_W1T);
    unsigned short* w2t    = (unsigned short*)(ws + OFF_W2T);
    unsigned*       bmapg  = (unsigned*)      (ws + OFF_BMAPG);
    int*            excnt  = (int*)           (ws + OFF_EXCNT);
    int*            exck   = (int*)           (ws + OFF_EXK);
    float*          excv   = (float*)         (ws + OFF_EXV);

    // zero dup bitmap + exception counters (contiguous region)
    hipMemsetAsync(bmapg, 0, 16777216 + 2048, stream);

    // 0) stripe-bucketed COO build + dup detection + weight prep
    k_bucket<<<BB, 512, 0, stream>>>(arows, acols, avals, rc, vpk, sstart,
                                     bmapg, excnt, exck, excv, W1, W2, w1t, w2t);

    // 1) supT(k-tiled) = bf16(emb[hyper] @ W1)^T (per batch)
    k_gemm1_mfma<<<1024, 256, 0, stream>>>(hyper, emb, w1t, supT);
    // 2) h1 = bf16(A @ sup1 + b1) -> d_out (bf16 [512][112])
    k_spmm_mfma<false><<<BB * 8, 512, 0, stream>>>(sstart, rc, vpk, supT,
                                                   excnt, exck, excv, b1, h1, out);
    // 3) supT(k-tiled) = bf16(h1 @ W2)^T (per batch)
    k_gemm2_mfma<<<1024, 256, 0, stream>>>(h1, w2t, supT);
    // 4) out = A @ sup2 + b2 -> d_out (fp32)
    k_spmm_mfma<true><<<BB * 8, 512, 0, stream>>>(sstart, rc, vpk, supT,
                                                  excnt, exck, excv, b2, h1, out);
}

// Round 21
// 296.518 us; speedup vs baseline: 2.0977x; 2.0977x over previous
//
#include <hip/hip_runtime.h>

// Problem constants (match reference setup_inputs)
#define BB   512
#define NN   512
#define NNZ  8192
#define EMB  64
#define HID  100
#define EXC  384             // per-batch dup-exception capacity (mean ~128, +23 sigma)
#define DUPC 0x7FFF          // col marker for dup placeholders (spmm skips via c<512)

// ---------------------------------------------------------------------------
// ws layout (bytes):
//   [0)          rc      int  [B*NNZ]  (row<<16|col, stripe-bucketed) 16,777,216
//   [16777216)   vpk     bf16 [B*NNZ]  (stripe-bucketed)               8,388,608
//   [25165824)   sstart  int  [B*9]                                       18,432
//   [26216448)   supT    bf16 [B][16kt][112col][32k]                  58,720,256
//   [84936704)   w1t     bf16 [112][64]                                   14,336
//   [84951040)   w2t     bf16 [112][128]                                  28,672
// h1 (bf16 [B][512][112]) lives in d_out; overwritten by final fp32 output.
// ---------------------------------------------------------------------------
#define OFF_RC      0
#define OFF_VPK     16777216
#define OFF_SSTART  25165824
#define OFF_SUPT    26216448
#define OFF_W1T     84936704
#define OFF_W2T     84951040

typedef __attribute__((ext_vector_type(8))) short short8;
typedef __attribute__((ext_vector_type(4))) float floatx4;

__device__ __forceinline__ unsigned short f2bf(float f) {
    unsigned u = __float_as_uint(f);
    unsigned r = (u + 0x7fffu + ((u >> 16) & 1u)) >> 16;
    return (unsigned short)r;
}

__device__ __forceinline__ float bf2f(unsigned short b) {
    return __uint_as_float((unsigned)b << 16);
}

__device__ __forceinline__ short8 pack8(float4 a, float4 b) {
    short8 s;
    s[0] = (short)f2bf(a.x); s[1] = (short)f2bf(a.y);
    s[2] = (short)f2bf(a.z); s[3] = (short)f2bf(a.w);
    s[4] = (short)f2bf(b.x); s[5] = (short)f2bf(b.y);
    s[6] = (short)f2bf(b.z); s[7] = (short)f2bf(b.w);
    return s;
}

// supT k-tiled addressing: elem(b, col, k) = b*57344 + (k>>5)*3584 + col*32 + (k&31)
__device__ __forceinline__ size_t supt_addr(int batch, int col, int k) {
    return (size_t)batch * 57344 + (size_t)(k >> 5) * 3584 + (size_t)col * 32 + (k & 31);
}

// A_d lane-linear tiled address (verified r13-r20): [m:4][kt:16][k8:4][r:16][k7:8]
__device__ __forceinline__ int ad_addr(int rr, int c) {
    return (rr >> 4) * 8192 + (c >> 5) * 512 + ((c >> 3) & 3) * 128 + (rr & 15) * 8 + (c & 7);
}

// ---------------------------------------------------------------------------
// k_bucket v3: stripe-bucketed COO + IN-LDS bitmap dedup, one round.
// Union trick: the 32 KB bitmap is dead after dup-detection (pre-scan
// barrier); the same 32 KB region then holds the bf16 value staging.
// LDS ~69 KB -> 2 blocks/CU, 512 blocks = single co-resident round.
// Dup losers: DUPC-marked in the stream (spmm skips with one compare) and
// resolved HERE (first-occurrence-owns fold + LDS stripe-bucket search).
// No global atomics anywhere (the r20 failure). Coalesced global I/O only.
// ---------------------------------------------------------------------------
__global__ __launch_bounds__(512) void k_bucket(
    const int* __restrict__ rows, const int* __restrict__ cols,
    const float* __restrict__ vals, int* __restrict__ rc,
    unsigned short* __restrict__ vpk, int* __restrict__ sstart,
    const float* __restrict__ W1, const float* __restrict__ W2,
    unsigned short* __restrict__ w1t, unsigned short* __restrict__ w2t)
{
    __shared__ int      rl[NNZ];          // 32 KB packed (r<<16)|c
    __shared__ unsigned ub[NN * 16];      // 32 KB union: bitmap, then bf16 vals
    __shared__ int      wcnt[8][8];       // [wave][stripe] counters/cursors
    __shared__ int      wbase[8][8];
    __shared__ int      exk[EXC];
    __shared__ float    exv[EXC];
    __shared__ int      exn;

    unsigned short* vh = (unsigned short*)ub;   // 16 KB view (post-barrier)

    const int b    = blockIdx.x;
    const int tid  = threadIdx.x;
    const int wave = tid >> 6;

    // striped weight prep: 21504 elements over 512 blocks (threads 0..41)
    {
        int pid = b + (tid << 9);
        if (pid < 7168) {
            int h = pid >> 6, k = pid & 63;
            w1t[pid] = f2bf((h < 100) ? W1[k * 100 + h] : 0.f);
        } else if (pid < 7168 + 14336) {
            int id2 = pid - 7168;
            int h = id2 >> 7, k = id2 & 127;
            w2t[id2] = f2bf((h < 100 && k < 100) ? W2[k * 100 + h] : 0.f);
        }
    }

    const int*   rb = rows + (size_t)b * NNZ;
    const int*   cb = cols + (size_t)b * NNZ;
    const float* vb = vals + (size_t)b * NNZ;

    // load all entries once into registers (16/thread)
    int rr[16], cc[16];
    float vv[16];
    #pragma unroll
    for (int i = 0; i < 16; ++i) {
        int idx = tid + i * 512;
        rr[i] = rb[idx]; cc[i] = cb[idx]; vv[i] = vb[idx];
    }

    // zero bitmap + counters
    #pragma unroll
    for (int i = 0; i < 16; ++i) ub[tid + i * 512] = 0u;
    if (tid < 64) ((int*)wcnt)[tid] = 0;
    if (tid == 0) exn = 0;
    __syncthreads();

    // P1: LDS-bitmap dup detection + per-(wave,stripe) histogram
    unsigned dupmask = 0;
    #pragma unroll
    for (int i = 0; i < 16; ++i) {
        unsigned bit = 1u << (cc[i] & 31);
        unsigned old = atomicOr(&ub[(rr[i] << 4) + (cc[i] >> 5)], bit);
        if (old & bit) {
            int e = atomicAdd(&exn, 1);
            if (e < EXC) {
                dupmask |= 1u << i;
                exk[e] = (rr[i] << 16) | cc[i];
                exv[e] = vv[i];
            }                                  // overflow: entry stays live
        }
        atomicAdd(&wcnt[wave][rr[i] >> 6], 1);
    }
    __syncthreads();                           // bitmap reads complete here

    // P2: tiny serial scan (64 values, stripe-major) + stripe_start out
    if (tid == 0) {
        int acc = 0;
        #pragma unroll
        for (int s = 0; s < 8; ++s) {
            sstart[b * 9 + s] = acc;
            #pragma unroll
            for (int w = 0; w < 8; ++w) { wbase[w][s] = acc; acc += wcnt[w][s]; }
        }
        sstart[b * 9 + 8] = NNZ;
    }
    __syncthreads();
    if (tid < 64) ((int*)wcnt)[tid] = ((int*)wbase)[tid];   // cursors
    __syncthreads();

    // P3: scatter into LDS staging (ub now reused as vh; bitmap dead)
    #pragma unroll
    for (int i = 0; i < 16; ++i) {
        int s = rr[i] >> 6;
        int pos = atomicAdd(&wcnt[wave][s], 1);
        bool dup = (dupmask >> i) & 1;
        rl[pos] = (rr[i] << 16) | (dup ? DUPC : cc[i]);
        vh[pos] = dup ? 0 : f2bf(vv[i]);
    }
    __syncthreads();

    // P3b: dup resolve, all in LDS. First occurrence of each key in the exc
    // list owns it, folds same-key values, then finds the (unique) winner
    // slot by scanning its stripe bucket (~1024 entries) and adds.
    {
        int ne = exn < EXC ? exn : EXC;
        for (int t = tid; t < ne; t += 512) {
            int key = exk[t];
            bool first = true;
            for (int j = 0; j < t; ++j)
                if (exk[j] == key) { first = false; break; }
            if (first) {
                float add = exv[t];
                for (int j = t + 1; j < ne; ++j)
                    if (exk[j] == key) add += exv[j];
                int s  = (key >> 16) >> 6;
                int lo = wbase[0][s];
                int hi = (s < 7) ? wbase[0][s + 1] : NNZ;
                for (int j = lo; j < hi; ++j) {
                    if (rl[j] == key) {
                        vh[j] = f2bf(bf2f(vh[j]) + add);
                        break;
                    }
                }
            }
        }
    }
    __syncthreads();

    // P4: fully coalesced writeback
    {
        int* orc = rc + (size_t)b * NNZ;
        #pragma unroll
        for (int i = 0; i < 16; ++i) {
            int idx = tid + i * 512;
            orc[idx] = rl[idx];
        }
        unsigned* ov = (unsigned*)(vpk + (size_t)b * NNZ);
        #pragma unroll
        for (int i = 0; i < 8; ++i) {
            int p = tid + i * 512;
            ov[p] = (unsigned)vh[2 * p] | ((unsigned)vh[2 * p + 1] << 16);
        }
    }
}

// ---------------------------------------------------------------------------
// GEMM1 (MFMA): supT(k-tiled) = bf16( emb[hyper] @ W1 )^T per batch. (r12-r20)
// ---------------------------------------------------------------------------
__global__ __launch_bounds__(256) void k_gemm1_mfma(
    const int* __restrict__ hyper, const float* __restrict__ emb,
    const unsigned short* __restrict__ w1t, unsigned short* __restrict__ supT)
{
    const int lane = threadIdx.x & 63, wave = threadIdx.x >> 6;
    const int l15 = lane & 15, g4 = lane >> 4;

    short8 bq[7][2];
    #pragma unroll
    for (int ct = 0; ct < 7; ++ct)
        #pragma unroll
        for (int kt = 0; kt < 2; ++kt)
            bq[ct][kt] = *(const short8*)(w1t + (ct * 16 + l15) * 64 + kt * 32 + g4 * 8);

    const int wsid = blockIdx.x * 4 + wave;
    #pragma unroll 2
    for (int i = 0; i < 4; ++i) {
        const int  rb   = wsid * 4 + i;
        const long base = (long)rb * 16;
        const int  rid  = hyper[base + l15];
        const float* ep = emb + (long)rid * EMB + g4 * 8;
        float4 f0 = *(const float4*)(ep);
        float4 f1 = *(const float4*)(ep + 4);
        float4 f2 = *(const float4*)(ep + 32);
        float4 f3 = *(const float4*)(ep + 36);
        short8 a0 = pack8(f0, f1);
        short8 a1 = pack8(f2, f3);

        floatx4 acc[7];
        #pragma unroll
        for (int ct = 0; ct < 7; ++ct) acc[ct] = (floatx4)0.f;
        #pragma unroll
        for (int ct = 0; ct < 7; ++ct) {
            acc[ct] = __builtin_amdgcn_mfma_f32_16x16x32_bf16(a0, bq[ct][0], acc[ct], 0, 0, 0);
            acc[ct] = __builtin_amdgcn_mfma_f32_16x16x32_bf16(a1, bq[ct][1], acc[ct], 0, 0, 0);
        }

        const int batch = rb >> 5;
        const int inrow = (rb & 31) * 16 + g4 * 4;
        #pragma unroll
        for (int ct = 0; ct < 7; ++ct) {
            int col = ct * 16 + l15;
            uint2 w;
            w.x = (unsigned)f2bf(acc[ct][0]) | ((unsigned)f2bf(acc[ct][1]) << 16);
            w.y = (unsigned)f2bf(acc[ct][2]) | ((unsigned)f2bf(acc[ct][3]) << 16);
            *(uint2*)(supT + supt_addr(batch, col, inrow)) = w;
        }
    }
}

// ---------------------------------------------------------------------------
// GEMM2 (MFMA): supT(k-tiled) = bf16( h1 @ W2 )^T, h1 bf16 [512][112]. (r12-r20)
// ---------------------------------------------------------------------------
__global__ __launch_bounds__(256) void k_gemm2_mfma(
    const unsigned short* __restrict__ h1, const unsigned short* __restrict__ w2t,
    unsigned short* __restrict__ supT)
{
    const int lane = threadIdx.x & 63, wave = threadIdx.x >> 6;
    const int l15 = lane & 15, g4 = lane >> 4;
    const int ct0 = (wave & 1) ? 4 : 0;

    short8 bq[4][4];
    #pragma unroll
    for (int ctl = 0; ctl < 4; ++ctl) {
        int ct = ct0 + ctl;
        if (ct < 7)
            #pragma unroll
            for (int kt = 0; kt < 4; ++kt)
                bq[ctl][kt] = *(const short8*)(w2t + (ct * 16 + l15) * 128 + kt * 32 + g4 * 8);
    }

    const int wp = blockIdx.x * 2 + (wave >> 1);
    #pragma unroll 2
    for (int i = 0; i < 8; ++i) {
        const int  rb   = wp * 8 + i;
        const long base = (long)rb * 16;
        const unsigned short* rp = h1 + (size_t)(base + l15) * 112;

        short8 a[4];
        #pragma unroll
        for (int kt = 0; kt < 4; ++kt) {
            int k0 = kt * 32 + g4 * 8;
            short8 av = (short8)(short)0;
            if (k0 < 112) av = *(const short8*)(rp + k0);
            a[kt] = av;
        }

        floatx4 acc[4];
        #pragma unroll
        for (int ctl = 0; ctl < 4; ++ctl) acc[ctl] = (floatx4)0.f;
        #pragma unroll
        for (int ctl = 0; ctl < 4; ++ctl) {
            if (ct0 + ctl < 7) {
                #pragma unroll
                for (int kt = 0; kt < 4; ++kt)
                    acc[ctl] = __builtin_amdgcn_mfma_f32_16x16x32_bf16(a[kt], bq[ctl][kt], acc[ctl], 0, 0, 0);
            }
        }

        const int batch = rb >> 5;
        const int inrow = (rb & 31) * 16 + g4 * 4;
        #pragma unroll
        for (int ctl = 0; ctl < 4; ++ctl) {
            if (ct0 + ctl < 7) {
                int col = (ct0 + ctl) * 16 + l15;
                uint2 w;
                w.x = (unsigned)f2bf(acc[ctl][0]) | ((unsigned)f2bf(acc[ctl][1]) << 16);
                w.y = (unsigned)f2bf(acc[ctl][2]) | ((unsigned)f2bf(acc[ctl][3]) << 16);
                *(uint2*)(supT + supt_addr(batch, col, inrow)) = w;
            }
        }
    }
}

// ---------------------------------------------------------------------------
// SpMM + bias via dense-A MFMA — r16's VERBATIM structure (measured <=64us):
// K-split 8-wave, full bfr[16] B-preload under launch_bounds(512,4), pc/pv
// early CSR loads, fully-unrolled P3 (rule #20). Only deltas vs r16:
// stripe segment from sstart, and the scatter predicated on c<512 (DUPC
// placeholders skipped — dups pre-merged by k_bucket). No dedup logic here.
// ---------------------------------------------------------------------------
template<bool FINAL>
__global__ __launch_bounds__(512, 4) void k_spmm_mfma(
    const int* __restrict__ sstart, const int* __restrict__ rc,
    const unsigned short* __restrict__ vpk, const unsigned short* __restrict__ supT,
    const float* __restrict__ bias, unsigned short* __restrict__ h1,
    float* __restrict__ out)
{
    __shared__ unsigned short Ad[64 * 512];      // 65,536 B -> 2 blocks/CU

    const int tid    = threadIdx.x;
    // XCD-locality swizzle (8 XCDs, round-robin blockIdx%8 -> XCD)
    const int xcd    = blockIdx.x & 7;
    const int local  = blockIdx.x >> 3;          // 0..511
    const int batch  = xcd * 64 + (local >> 3);
    const int stripe = local & 7;
    const int r0     = stripe * 64;

    const int lane = tid & 63, wave = tid >> 6;
    const int l15 = lane & 15, g4 = lane >> 4;
    const int ng  = wave & 3, kh = wave >> 2;
    const int nt0 = ng * 2;
    const bool two = (nt0 + 1) < 7;              // ng=3 owns only n-tile 6
    const int ktb = kh * 8;

    // P0a: issue this stripe's COO entries EARLY (contiguous segment)
    const int s0 = sstart[batch * 9 + stripe];
    const int e0 = sstart[batch * 9 + stripe + 1];
    const int*            rcb = rc + (size_t)batch * NNZ;
    const unsigned short* vvb = vpk + (size_t)batch * NNZ;
    int            pc[3];
    unsigned short pv[3];
    #pragma unroll
    for (int i = 0; i < 3; ++i) {
        int idx = s0 + tid + i * 512;
        bool ok = idx < e0;
        pc[i] = ok ? rcb[idx] : 0;
        pv[i] = ok ? vvb[idx] : 0;
    }

    // P0b: issue ALL 16 B fragments EARLY (r16-proven; latency hides under
    // P1/P2; launch_bounds(512,4) pins VGPR <= 128)
    const unsigned short* b0p = supT + (size_t)batch * 57344 + (size_t)ktb * 3584
                               + (nt0 * 16 + l15) * 32 + g4 * 8;
    const unsigned short* b1p = b0p + 512;       // next n-tile
    short8 bfr[16];
    #pragma unroll
    for (int kt = 0; kt < 8; ++kt) {
        bfr[2 * kt] = *(const short8*)(b0p + (size_t)kt * 3584);
        if (two) bfr[2 * kt + 1] = *(const short8*)(b1p + (size_t)kt * 3584);
        else     bfr[2 * kt + 1] = (short8)(short)0;
    }

    // P1: zero A_d (4096 uint4)
    {
        uint4* z = (uint4*)Ad;
        #pragma unroll
        for (int i = 0; i < 8; ++i) z[tid + i * 512] = make_uint4(0u, 0u, 0u, 0u);
    }
    __syncthreads();

    // P2: predicated scatter (c==DUPC placeholders skipped; no atomics)
    #pragma unroll
    for (int i = 0; i < 3; ++i) {
        int idx = s0 + tid + i * 512;
        if (idx < e0) {
            int rr = ((pc[i] >> 16) & 0xffff) - r0;   // 0..63
            int c  = pc[i] & 0xffff;
            if (c < 512) Ad[ad_addr(rr, c)] = pv[i];
        }
    }
    // overflow fallback (stripe count > 1536: ~never, correctness only)
    for (int idx = s0 + 1536 + tid; idx < e0; idx += 512) {
        int p = rcb[idx];
        int rr = ((p >> 16) & 0xffff) - r0;
        int c  = p & 0xffff;
        if (c < 512) Ad[ad_addr(rr, c)] = vvb[idx];
    }
    __syncthreads();

    // P3: pure LDS-read + MFMA (B in registers; fully unrolled — rule #20)
    const unsigned short* ap = Ad + (size_t)ktb * 512 + lane * 8;  // lane-linear

    floatx4 acc[2][4];
    #pragma unroll
    for (int n = 0; n < 2; ++n)
        #pragma unroll
        for (int m = 0; m < 4; ++m) acc[n][m] = (floatx4)0.f;

    #pragma unroll
    for (int kt = 0; kt < 8; ++kt) {
        #pragma unroll
        for (int m = 0; m < 4; ++m) {
            short8 a = *(const short8*)(ap + m * 8192 + kt * 512);
            acc[0][m] = __builtin_amdgcn_mfma_f32_16x16x32_bf16(a, bfr[2 * kt], acc[0][m], 0, 0, 0);
            if (two)
                acc[1][m] = __builtin_amdgcn_mfma_f32_16x16x32_bf16(a, bfr[2 * kt + 1], acc[1][m], 0, 0, 0);
        }
    }
    __syncthreads();                             // all MFMAs done; A_d dead

    // P4: k-half reduction through LDS. redu[slot:4][i:32][lane:64] f32 (32KB)
    float* redu = (float*)Ad;
    if (kh == 1) {
        #pragma unroll
        for (int nn = 0; nn < 2; ++nn)
            #pragma unroll
            for (int m = 0; m < 4; ++m)
                #pragma unroll
                for (int q = 0; q < 4; ++q)
                    redu[ng * 2048 + ((nn * 4 + m) * 4 + q) * 64 + lane] = acc[nn][m][q];
    }
    __syncthreads();

    // P5: waves kh=0 add partner partials and stage C (+bias) at byte 32768
    if (kh == 0) {
        #pragma unroll
        for (int nn = 0; nn < 2; ++nn)
            #pragma unroll
            for (int m = 0; m < 4; ++m)
                #pragma unroll
                for (int q = 0; q < 4; ++q)
                    acc[nn][m][q] += redu[ng * 2048 + ((nn * 4 + m) * 4 + q) * 64 + lane];

        if (FINAL) {
            float* st = (float*)((char*)Ad + 32768);           // [64][112] f32
            #pragma unroll
            for (int nn = 0; nn < 2; ++nn) {
                int nt = nt0 + nn;
                if (nt >= 7) break;
                int col = nt * 16 + l15;
                float bi = (col < HID) ? bias[col] : 0.f;
                #pragma unroll
                for (int m = 0; m < 4; ++m) {
                    int row = m * 16 + g4 * 4;
                    #pragma unroll
                    for (int q = 0; q < 4; ++q)
                        st[(row + q) * 112 + col] = acc[nn][m][q] + bi;
                }
            }
        } else {
            unsigned short* st = (unsigned short*)((char*)Ad + 32768);  // [64][112] bf16
            #pragma unroll
            for (int nn = 0; nn < 2; ++nn) {
                int nt = nt0 + nn;
                if (nt >= 7) break;
                int col = nt * 16 + l15;
                float bi = (col < HID) ? bias[col] : 0.f;      // pad cols: acc==0 -> 0
                #pragma unroll
                for (int m = 0; m < 4; ++m) {
                    int row = m * 16 + g4 * 4;
                    #pragma unroll
                    for (int q = 0; q < 4; ++q)
                        st[(row + q) * 112 + col] = f2bf(acc[nn][m][q] + bi);
                }
            }
        }
    }
    __syncthreads();

    // P6: coalesced copy-out, all 512 threads
    if (FINAL) {
        const float* st = (const float*)((char*)Ad + 32768);
        #pragma unroll
        for (int i = 0; i < 4; ++i) {
            int flat = tid + i * 512;
            if (flat < 1600) {                   // 64 rows x 25 float4
                int row = flat / 25, wi = flat - row * 25;
                float4 v = *(const float4*)(st + row * 112 + wi * 4);
                *(float4*)(out + ((size_t)batch * NN + r0 + row) * HID + wi * 4) = v;
            }
        }
    } else {
        const unsigned short* st = (const unsigned short*)((char*)Ad + 32768);
        #pragma unroll
        for (int i = 0; i < 2; ++i) {
            int flat = tid + i * 512;
            if (flat < 896) {                    // 64 rows x 14 uint4
                int row = flat / 14, wi = flat - row * 14;
                uint4 v = *(const uint4*)(st + row * 112 + wi * 8);
                *(uint4*)(h1 + ((size_t)batch * NN + r0 + row) * 112 + wi * 8) = v;
            }
        }
    }
}

// ---------------------------------------------------------------------------
extern "C" void kernel_launch(void* const* d_in, const int* in_sizes, int n_in,
                              void* d_out, int out_size, void* d_ws, size_t ws_size,
                              hipStream_t stream)
{
    const int*   hyper = (const int*)  d_in[0];
    const int*   arows = (const int*)  d_in[1];
    const int*   acols = (const int*)  d_in[2];
    const float* avals = (const float*)d_in[3];
    const float* emb   = (const float*)d_in[4];
    const float* W1    = (const float*)d_in[5];
    const float* b1    = (const float*)d_in[6];
    const float* W2    = (const float*)d_in[7];
    const float* b2    = (const float*)d_in[8];

    float*          out = (float*)d_out;
    unsigned short* h1  = (unsigned short*)d_out;   // bf16 [B][512][112] view
    char*           ws  = (char*)d_ws;

    int*            rc     = (int*)           (ws + OFF_RC);
    unsigned short* vpk    = (unsigned short*)(ws + OFF_VPK);
    int*            sstart = (int*)           (ws + OFF_SSTART);
    unsigned short* supT   = (unsigned short*)(ws + OFF_SUPT);
    unsigned short* w1t    = (unsigned short*)(ws + OFF_W1T);
    unsigned short* w2t    = (unsigned short*)(ws + OFF_W2T);

    // 0) stripe-bucketed COO build + in-LDS dedup + weight prep (one round)
    k_bucket<<<BB, 512, 0, stream>>>(arows, acols, avals, rc, vpk, sstart,
                                     W1, W2, w1t, w2t);

    // 1) supT(k-tiled) = bf16(emb[hyper] @ W1)^T (per batch)
    k_gemm1_mfma<<<1024, 256, 0, stream>>>(hyper, emb, w1t, supT);
    // 2) h1 = bf16(A @ sup1 + b1) -> d_out (bf16 [512][112])
    k_spmm_mfma<false><<<BB * 8, 512, 0, stream>>>(sstart, rc, vpk, supT, b1, h1, out);
    // 3) supT(k-tiled) = bf16(h1 @ W2)^T (per batch)
    k_gemm2_mfma<<<1024, 256, 0, stream>>>(h1, w2t, supT);
    // 4) out = A @ sup2 + b2 -> d_out (fp32)
    k_spmm_mfma<true><<<BB * 8, 512, 0, stream>>>(sstart, rc, vpk, supT, b2, h1, out);
}

// Round 22
// 197.165 us; speedup vs baseline: 3.1547x; 1.5039x over previous
//
#include <hip/hip_runtime.h>

// Problem constants (match reference setup_inputs)
#define BB   512
#define NN   512
#define NNZ  8192
#define EMB  64
#define HID  100
#define DUPC 0x7FFF          // col marker for dup placeholders (spmm skips via c<512)
#define HTSZ 512             // LDS dup hash-table slots (~128 keys expected, 25% load)

// ---------------------------------------------------------------------------
// ws layout (bytes):
//   [0)          rc      int  [B*NNZ]  (row<<16|col, stripe-bucketed) 16,777,216
//   [16777216)   vpk     bf16 [B*NNZ]  (stripe-bucketed)               8,388,608
//   [25165824)   sstart  int  [B*9]                                       18,432
//   [26216448)   supT    bf16 [B][16kt][112col][32k]                  58,720,256
//   [84936704)   w1t     bf16 [112][64]                                   14,336
//   [84951040)   w2t     bf16 [112][128]                                  28,672
// h1 (bf16 [B][512][112]) lives in d_out; overwritten by final fp32 output.
// ---------------------------------------------------------------------------
#define OFF_RC      0
#define OFF_VPK     16777216
#define OFF_SSTART  25165824
#define OFF_SUPT    26216448
#define OFF_W1T     84936704
#define OFF_W2T     84951040

typedef __attribute__((ext_vector_type(8))) short short8;
typedef __attribute__((ext_vector_type(4))) float floatx4;

__device__ __forceinline__ unsigned short f2bf(float f) {
    unsigned u = __float_as_uint(f);
    unsigned r = (u + 0x7fffu + ((u >> 16) & 1u)) >> 16;
    return (unsigned short)r;
}

__device__ __forceinline__ float bf2f(unsigned short b) {
    return __uint_as_float((unsigned)b << 16);
}

__device__ __forceinline__ short8 pack8(float4 a, float4 b) {
    short8 s;
    s[0] = (short)f2bf(a.x); s[1] = (short)f2bf(a.y);
    s[2] = (short)f2bf(a.z); s[3] = (short)f2bf(a.w);
    s[4] = (short)f2bf(b.x); s[5] = (short)f2bf(b.y);
    s[6] = (short)f2bf(b.z); s[7] = (short)f2bf(b.w);
    return s;
}

__device__ __forceinline__ int keyhash(int key) {
    return (int)(((unsigned)key * 2654435761u) >> 23) & (HTSZ - 1);
}

// supT k-tiled addressing: elem(b, col, k) = b*57344 + (k>>5)*3584 + col*32 + (k&31)
__device__ __forceinline__ size_t supt_addr(int batch, int col, int k) {
    return (size_t)batch * 57344 + (size_t)(k >> 5) * 3584 + (size_t)col * 32 + (k & 31);
}

// A_d lane-linear tiled address (verified r13-r21): [m:4][kt:16][k8:4][r:16][k7:8]
__device__ __forceinline__ int ad_addr(int rr, int c) {
    return (rr >> 4) * 8192 + (c >> 5) * 512 + ((c >> 3) & 3) * 128 + (rr & 15) * 8 + (c & 7);
}

// ---------------------------------------------------------------------------
// k_bucket v4: stripe-bucketed COO + in-LDS bitmap dedup + HASH-TABLE fold.
// Fix vs r21 (150us): the dup resolve was a serial ~1024-iteration LDS
// search per dup key (the r13 mistake repeated). Now: losers find-or-insert
// (atomicCAS probe, expected 1) + atomicAdd their value into a 512-slot LDS
// hash table in P1; winners probe ONCE in P3 (expected 1-2 independent LDS
// reads) and fold the sum. No bucket scans anywhere. One round, 2 blocks/CU,
// no global atomics, coalesced global I/O.
// ---------------------------------------------------------------------------
__global__ __launch_bounds__(512) void k_bucket(
    const int* __restrict__ rows, const int* __restrict__ cols,
    const float* __restrict__ vals, int* __restrict__ rc,
    unsigned short* __restrict__ vpk, int* __restrict__ sstart,
    const float* __restrict__ W1, const float* __restrict__ W2,
    unsigned short* __restrict__ w1t, unsigned short* __restrict__ w2t)
{
    __shared__ int      rl[NNZ];          // 32 KB packed (r<<16)|c
    __shared__ unsigned ub[NN * 16];      // 32 KB union: bitmap, then bf16 vals
    __shared__ int      wcnt[8][8];       // [wave][stripe] counters/cursors
    __shared__ int      wbase[8][8];
    __shared__ int      htk[HTSZ];        // 2 KB dup keys
    __shared__ float    htv[HTSZ];        // 2 KB dup value sums

    unsigned short* vh = (unsigned short*)ub;   // 16 KB view (post-barrier)

    const int b    = blockIdx.x;
    const int tid  = threadIdx.x;
    const int wave = tid >> 6;

    // striped weight prep: 21504 elements over 512 blocks (threads 0..41)
    {
        int pid = b + (tid << 9);
        if (pid < 7168) {
            int h = pid >> 6, k = pid & 63;
            w1t[pid] = f2bf((h < 100) ? W1[k * 100 + h] : 0.f);
        } else if (pid < 7168 + 14336) {
            int id2 = pid - 7168;
            int h = id2 >> 7, k = id2 & 127;
            w2t[id2] = f2bf((h < 100 && k < 100) ? W2[k * 100 + h] : 0.f);
        }
    }

    const int*   rb = rows + (size_t)b * NNZ;
    const int*   cb = cols + (size_t)b * NNZ;
    const float* vb = vals + (size_t)b * NNZ;

    // load all entries once into registers (16/thread)
    int rr[16], cc[16];
    float vv[16];
    #pragma unroll
    for (int i = 0; i < 16; ++i) {
        int idx = tid + i * 512;
        rr[i] = rb[idx]; cc[i] = cb[idx]; vv[i] = vb[idx];
    }

    // zero bitmap + hash table + counters
    #pragma unroll
    for (int i = 0; i < 16; ++i) ub[tid + i * 512] = 0u;
    htk[tid] = -1;
    htv[tid] = 0.f;
    if (tid < 64) ((int*)wcnt)[tid] = 0;
    __syncthreads();

    // P1: bitmap dup detection; losers find-or-insert + add into hash table
    unsigned dupmask = 0;
    #pragma unroll
    for (int i = 0; i < 16; ++i) {
        unsigned bit = 1u << (cc[i] & 31);
        unsigned old = atomicOr(&ub[(rr[i] << 4) + (cc[i] >> 5)], bit);
        if (old & bit) {
            dupmask |= 1u << i;
            int key = (rr[i] << 16) | cc[i];
            int h = keyhash(key);
            bool placed = false;
            for (int p = 0; p < HTSZ; ++p) {
                int prev = atomicCAS(&htk[h], -1, key);
                if (prev == -1 || prev == key) { placed = true; break; }
                h = (h + 1) & (HTSZ - 1);
            }
            if (placed) atomicAdd(&htv[h], vv[i]);
            else        dupmask &= ~(1u << i);   // table full (~impossible): keep entry
        }
        atomicAdd(&wcnt[wave][rr[i] >> 6], 1);
    }
    __syncthreads();                           // bitmap + hash inserts complete

    // P2: tiny serial scan (64 values, stripe-major) + stripe_start out
    if (tid == 0) {
        int acc = 0;
        #pragma unroll
        for (int s = 0; s < 8; ++s) {
            sstart[b * 9 + s] = acc;
            #pragma unroll
            for (int w = 0; w < 8; ++w) { wbase[w][s] = acc; acc += wcnt[w][s]; }
        }
        sstart[b * 9 + 8] = NNZ;
    }
    __syncthreads();
    if (tid < 64) ((int*)wcnt)[tid] = ((int*)wbase)[tid];   // cursors
    __syncthreads();

    // P3: scatter into LDS staging (ub reused as vh — bitmap dead).
    // Winners probe the hash table once and fold the dup sum (f32) in.
    #pragma unroll
    for (int i = 0; i < 16; ++i) {
        int s = rr[i] >> 6;
        int pos = atomicAdd(&wcnt[wave][s], 1);
        bool dup = (dupmask >> i) & 1;
        float v = vv[i];
        if (!dup) {
            int key = (rr[i] << 16) | cc[i];
            int h = keyhash(key);
            for (int p = 0; p < HTSZ; ++p) {
                int k2 = htk[h];
                if (k2 == -1) break;
                if (k2 == key) { v += htv[h]; break; }
                h = (h + 1) & (HTSZ - 1);
            }
        }
        rl[pos] = (rr[i] << 16) | (dup ? DUPC : cc[i]);
        vh[pos] = dup ? 0 : f2bf(v);
    }
    __syncthreads();

    // P4: fully coalesced writeback
    {
        int* orc = rc + (size_t)b * NNZ;
        #pragma unroll
        for (int i = 0; i < 16; ++i) {
            int idx = tid + i * 512;
            orc[idx] = rl[idx];
        }
        unsigned* ov = (unsigned*)(vpk + (size_t)b * NNZ);
        #pragma unroll
        for (int i = 0; i < 8; ++i) {
            int p = tid + i * 512;
            ov[p] = (unsigned)vh[2 * p] | ((unsigned)vh[2 * p + 1] << 16);
        }
    }
}

// ---------------------------------------------------------------------------
// GEMM1 (MFMA): supT(k-tiled) = bf16( emb[hyper] @ W1 )^T per batch. (r12-r21)
// ---------------------------------------------------------------------------
__global__ __launch_bounds__(256) void k_gemm1_mfma(
    const int* __restrict__ hyper, const float* __restrict__ emb,
    const unsigned short* __restrict__ w1t, unsigned short* __restrict__ supT)
{
    const int lane = threadIdx.x & 63, wave = threadIdx.x >> 6;
    const int l15 = lane & 15, g4 = lane >> 4;

    short8 bq[7][2];
    #pragma unroll
    for (int ct = 0; ct < 7; ++ct)
        #pragma unroll
        for (int kt = 0; kt < 2; ++kt)
            bq[ct][kt] = *(const short8*)(w1t + (ct * 16 + l15) * 64 + kt * 32 + g4 * 8);

    const int wsid = blockIdx.x * 4 + wave;
    #pragma unroll 2
    for (int i = 0; i < 4; ++i) {
        const int  rb   = wsid * 4 + i;
        const long base = (long)rb * 16;
        const int  rid  = hyper[base + l15];
        const float* ep = emb + (long)rid * EMB + g4 * 8;
        float4 f0 = *(const float4*)(ep);
        float4 f1 = *(const float4*)(ep + 4);
        float4 f2 = *(const float4*)(ep + 32);
        float4 f3 = *(const float4*)(ep + 36);
        short8 a0 = pack8(f0, f1);
        short8 a1 = pack8(f2, f3);

        floatx4 acc[7];
        #pragma unroll
        for (int ct = 0; ct < 7; ++ct) acc[ct] = (floatx4)0.f;
        #pragma unroll
        for (int ct = 0; ct < 7; ++ct) {
            acc[ct] = __builtin_amdgcn_mfma_f32_16x16x32_bf16(a0, bq[ct][0], acc[ct], 0, 0, 0);
            acc[ct] = __builtin_amdgcn_mfma_f32_16x16x32_bf16(a1, bq[ct][1], acc[ct], 0, 0, 0);
        }

        const int batch = rb >> 5;
        const int inrow = (rb & 31) * 16 + g4 * 4;
        #pragma unroll
        for (int ct = 0; ct < 7; ++ct) {
            int col = ct * 16 + l15;
            uint2 w;
            w.x = (unsigned)f2bf(acc[ct][0]) | ((unsigned)f2bf(acc[ct][1]) << 16);
            w.y = (unsigned)f2bf(acc[ct][2]) | ((unsigned)f2bf(acc[ct][3]) << 16);
            *(uint2*)(supT + supt_addr(batch, col, inrow)) = w;
        }
    }
}

// ---------------------------------------------------------------------------
// GEMM2 (MFMA): supT(k-tiled) = bf16( h1 @ W2 )^T, h1 bf16 [512][112]. (r12-r21)
// ---------------------------------------------------------------------------
__global__ __launch_bounds__(256) void k_gemm2_mfma(
    const unsigned short* __restrict__ h1, const unsigned short* __restrict__ w2t,
    unsigned short* __restrict__ supT)
{
    const int lane = threadIdx.x & 63, wave = threadIdx.x >> 6;
    const int l15 = lane & 15, g4 = lane >> 4;
    const int ct0 = (wave & 1) ? 4 : 0;

    short8 bq[4][4];
    #pragma unroll
    for (int ctl = 0; ctl < 4; ++ctl) {
        int ct = ct0 + ctl;
        if (ct < 7)
            #pragma unroll
            for (int kt = 0; kt < 4; ++kt)
                bq[ctl][kt] = *(const short8*)(w2t + (ct * 16 + l15) * 128 + kt * 32 + g4 * 8);
    }

    const int wp = blockIdx.x * 2 + (wave >> 1);
    #pragma unroll 2
    for (int i = 0; i < 8; ++i) {
        const int  rb   = wp * 8 + i;
        const long base = (long)rb * 16;
        const unsigned short* rp = h1 + (size_t)(base + l15) * 112;

        short8 a[4];
        #pragma unroll
        for (int kt = 0; kt < 4; ++kt) {
            int k0 = kt * 32 + g4 * 8;
            short8 av = (short8)(short)0;
            if (k0 < 112) av = *(const short8*)(rp + k0);
            a[kt] = av;
        }

        floatx4 acc[4];
        #pragma unroll
        for (int ctl = 0; ctl < 4; ++ctl) acc[ctl] = (floatx4)0.f;
        #pragma unroll
        for (int ctl = 0; ctl < 4; ++ctl) {
            if (ct0 + ctl < 7) {
                #pragma unroll
                for (int kt = 0; kt < 4; ++kt)
                    acc[ctl] = __builtin_amdgcn_mfma_f32_16x16x32_bf16(a[kt], bq[ctl][kt], acc[ctl], 0, 0, 0);
            }
        }

        const int batch = rb >> 5;
        const int inrow = (rb & 31) * 16 + g4 * 4;
        #pragma unroll
        for (int ctl = 0; ctl < 4; ++ctl) {
            if (ct0 + ctl < 7) {
                int col = (ct0 + ctl) * 16 + l15;
                uint2 w;
                w.x = (unsigned)f2bf(acc[ctl][0]) | ((unsigned)f2bf(acc[ctl][1]) << 16);
                w.y = (unsigned)f2bf(acc[ctl][2]) | ((unsigned)f2bf(acc[ctl][3]) << 16);
                *(uint2*)(supT + supt_addr(batch, col, inrow)) = w;
            }
        }
    }
}

// ---------------------------------------------------------------------------
// SpMM + bias via dense-A MFMA — r16's verbatim structure (verified r21:
// out of top-5). K-split 8-wave, full bfr[16] B-preload, predicated scatter
// (DUPC skipped), fully-unrolled P3.
// ---------------------------------------------------------------------------
template<bool FINAL>
__global__ __launch_bounds__(512, 4) void k_spmm_mfma(
    const int* __restrict__ sstart, const int* __restrict__ rc,
    const unsigned short* __restrict__ vpk, const unsigned short* __restrict__ supT,
    const float* __restrict__ bias, unsigned short* __restrict__ h1,
    float* __restrict__ out)
{
    __shared__ unsigned short Ad[64 * 512];      // 65,536 B -> 2 blocks/CU

    const int tid    = threadIdx.x;
    // XCD-locality swizzle (8 XCDs, round-robin blockIdx%8 -> XCD)
    const int xcd    = blockIdx.x & 7;
    const int local  = blockIdx.x >> 3;          // 0..511
    const int batch  = xcd * 64 + (local >> 3);
    const int stripe = local & 7;
    const int r0     = stripe * 64;

    const int lane = tid & 63, wave = tid >> 6;
    const int l15 = lane & 15, g4 = lane >> 4;
    const int ng  = wave & 3, kh = wave >> 2;
    const int nt0 = ng * 2;
    const bool two = (nt0 + 1) < 7;              // ng=3 owns only n-tile 6
    const int ktb = kh * 8;

    // P0a: issue this stripe's COO entries EARLY (contiguous segment)
    const int s0 = sstart[batch * 9 + stripe];
    const int e0 = sstart[batch * 9 + stripe + 1];
    const int*            rcb = rc + (size_t)batch * NNZ;
    const unsigned short* vvb = vpk + (size_t)batch * NNZ;
    int            pc[3];
    unsigned short pv[3];
    #pragma unroll
    for (int i = 0; i < 3; ++i) {
        int idx = s0 + tid + i * 512;
        bool ok = idx < e0;
        pc[i] = ok ? rcb[idx] : 0;
        pv[i] = ok ? vvb[idx] : 0;
    }

    // P0b: issue ALL 16 B fragments EARLY (r16-proven)
    const unsigned short* b0p = supT + (size_t)batch * 57344 + (size_t)ktb * 3584
                               + (nt0 * 16 + l15) * 32 + g4 * 8;
    const unsigned short* b1p = b0p + 512;       // next n-tile
    short8 bfr[16];
    #pragma unroll
    for (int kt = 0; kt < 8; ++kt) {
        bfr[2 * kt] = *(const short8*)(b0p + (size_t)kt * 3584);
        if (two) bfr[2 * kt + 1] = *(const short8*)(b1p + (size_t)kt * 3584);
        else     bfr[2 * kt + 1] = (short8)(short)0;
    }

    // P1: zero A_d (4096 uint4)
    {
        uint4* z = (uint4*)Ad;
        #pragma unroll
        for (int i = 0; i < 8; ++i) z[tid + i * 512] = make_uint4(0u, 0u, 0u, 0u);
    }
    __syncthreads();

    // P2: predicated scatter (c==DUPC placeholders skipped; no atomics)
    #pragma unroll
    for (int i = 0; i < 3; ++i) {
        int idx = s0 + tid + i * 512;
        if (idx < e0) {
            int rr = ((pc[i] >> 16) & 0xffff) - r0;   // 0..63
            int c  = pc[i] & 0xffff;
            if (c < 512) Ad[ad_addr(rr, c)] = pv[i];
        }
    }
    // overflow fallback (stripe count > 1536: ~never, correctness only)
    for (int idx = s0 + 1536 + tid; idx < e0; idx += 512) {
        int p = rcb[idx];
        int rr = ((p >> 16) & 0xffff) - r0;
        int c  = p & 0xffff;
        if (c < 512) Ad[ad_addr(rr, c)] = vvb[idx];
    }
    __syncthreads();

    // P3: pure LDS-read + MFMA (B in registers; fully unrolled — rule #20)
    const unsigned short* ap = Ad + (size_t)ktb * 512 + lane * 8;  // lane-linear

    floatx4 acc[2][4];
    #pragma unroll
    for (int n = 0; n < 2; ++n)
        #pragma unroll
        for (int m = 0; m < 4; ++m) acc[n][m] = (floatx4)0.f;

    #pragma unroll
    for (int kt = 0; kt < 8; ++kt) {
        #pragma unroll
        for (int m = 0; m < 4; ++m) {
            short8 a = *(const short8*)(ap + m * 8192 + kt * 512);
            acc[0][m] = __builtin_amdgcn_mfma_f32_16x16x32_bf16(a, bfr[2 * kt], acc[0][m], 0, 0, 0);
            if (two)
                acc[1][m] = __builtin_amdgcn_mfma_f32_16x16x32_bf16(a, bfr[2 * kt + 1], acc[1][m], 0, 0, 0);
        }
    }
    __syncthreads();                             // all MFMAs done; A_d dead

    // P4: k-half reduction through LDS. redu[slot:4][i:32][lane:64] f32 (32KB)
    float* redu = (float*)Ad;
    if (kh == 1) {
        #pragma unroll
        for (int nn = 0; nn < 2; ++nn)
            #pragma unroll
            for (int m = 0; m < 4; ++m)
                #pragma unroll
                for (int q = 0; q < 4; ++q)
                    redu[ng * 2048 + ((nn * 4 + m) * 4 + q) * 64 + lane] = acc[nn][m][q];
    }
    __syncthreads();

    // P5: waves kh=0 add partner partials and stage C (+bias) at byte 32768
    if (kh == 0) {
        #pragma unroll
        for (int nn = 0; nn < 2; ++nn)
            #pragma unroll
            for (int m = 0; m < 4; ++m)
                #pragma unroll
                for (int q = 0; q < 4; ++q)
                    acc[nn][m][q] += redu[ng * 2048 + ((nn * 4 + m) * 4 + q) * 64 + lane];

        if (FINAL) {
            float* st = (float*)((char*)Ad + 32768);           // [64][112] f32
            #pragma unroll
            for (int nn = 0; nn < 2; ++nn) {
                int nt = nt0 + nn;
                if (nt >= 7) break;
                int col = nt * 16 + l15;
                float bi = (col < HID) ? bias[col] : 0.f;
                #pragma unroll
                for (int m = 0; m < 4; ++m) {
                    int row = m * 16 + g4 * 4;
                    #pragma unroll
                    for (int q = 0; q < 4; ++q)
                        st[(row + q) * 112 + col] = acc[nn][m][q] + bi;
                }
            }
        } else {
            unsigned short* st = (unsigned short*)((char*)Ad + 32768);  // [64][112] bf16
            #pragma unroll
            for (int nn = 0; nn < 2; ++nn) {
                int nt = nt0 + nn;
                if (nt >= 7) break;
                int col = nt * 16 + l15;
                float bi = (col < HID) ? bias[col] : 0.f;      // pad cols: acc==0 -> 0
                #pragma unroll
                for (int m = 0; m < 4; ++m) {
                    int row = m * 16 + g4 * 4;
                    #pragma unroll
                    for (int q = 0; q < 4; ++q)
                        st[(row + q) * 112 + col] = f2bf(acc[nn][m][q] + bi);
                }
            }
        }
    }
    __syncthreads();

    // P6: coalesced copy-out, all 512 threads
    if (FINAL) {
        const float* st = (const float*)((char*)Ad + 32768);
        #pragma unroll
        for (int i = 0; i < 4; ++i) {
            int flat = tid + i * 512;
            if (flat < 1600) {                   // 64 rows x 25 float4
                int row = flat / 25, wi = flat - row * 25;
                float4 v = *(const float4*)(st + row * 112 + wi * 4);
                *(float4*)(out + ((size_t)batch * NN + r0 + row) * HID + wi * 4) = v;
            }
        }
    } else {
        const unsigned short* st = (const unsigned short*)((char*)Ad + 32768);
        #pragma unroll
        for (int i = 0; i < 2; ++i) {
            int flat = tid + i * 512;
            if (flat < 896) {                    // 64 rows x 14 uint4
                int row = flat / 14, wi = flat - row * 14;
                uint4 v = *(const uint4*)(st + row * 112 + wi * 8);
                *(uint4*)(h1 + ((size_t)batch * NN + r0 + row) * 112 + wi * 8) = v;
            }
        }
    }
}

// ---------------------------------------------------------------------------
extern "C" void kernel_launch(void* const* d_in, const int* in_sizes, int n_in,
                              void* d_out, int out_size, void* d_ws, size_t ws_size,
                              hipStream_t stream)
{
    const int*   hyper = (const int*)  d_in[0];
    const int*   arows = (const int*)  d_in[1];
    const int*   acols = (const int*)  d_in[2];
    const float* avals = (const float*)d_in[3];
    const float* emb   = (const float*)d_in[4];
    const float* W1    = (const float*)d_in[5];
    const float* b1    = (const float*)d_in[6];
    const float* W2    = (const float*)d_in[7];
    const float* b2    = (const float*)d_in[8];

    float*          out = (float*)d_out;
    unsigned short* h1  = (unsigned short*)d_out;   // bf16 [B][512][112] view
    char*           ws  = (char*)d_ws;

    int*            rc     = (int*)           (ws + OFF_RC);
    unsigned short* vpk    = (unsigned short*)(ws + OFF_VPK);
    int*            sstart = (int*)           (ws + OFF_SSTART);
    unsigned short* supT   = (unsigned short*)(ws + OFF_SUPT);
    unsigned short* w1t    = (unsigned short*)(ws + OFF_W1T);
    unsigned short* w2t    = (unsigned short*)(ws + OFF_W2T);

    // 0) stripe-bucketed COO build + hash-table dedup + weight prep (one round)
    k_bucket<<<BB, 512, 0, stream>>>(arows, acols, avals, rc, vpk, sstart,
                                     W1, W2, w1t, w2t);

    // 1) supT(k-tiled) = bf16(emb[hyper] @ W1)^T (per batch)
    k_gemm1_mfma<<<1024, 256, 0, stream>>>(hyper, emb, w1t, supT);
    // 2) h1 = bf16(A @ sup1 + b1) -> d_out (bf16 [512][112])
    k_spmm_mfma<false><<<BB * 8, 512, 0, stream>>>(sstart, rc, vpk, supT, b1, h1, out);
    // 3) supT(k-tiled) = bf16(h1 @ W2)^T (per batch)
    k_gemm2_mfma<<<1024, 256, 0, stream>>>(h1, w2t, supT);
    // 4) out = A @ sup2 + b2 -> d_out (fp32)
    k_spmm_mfma<true><<<BB * 8, 512, 0, stream>>>(sstart, rc, vpk, supT, b2, h1, out);
}